// Round 1
// baseline (213.502 us; speedup 1.0000x reference)
//
#include <hip/hip_runtime.h>
#include <math.h>

#define TT 128
#define IN_CH 32
#define NPATH 256
#define SIGCH 7380
#define K1 29520
#define N1 512
#define N2 256
#define KSPLIT 41
#define KCH 720
#define BK 48

// ---------------- Kernel 1: conv + time-augment + depth-4 signature ----------------
__global__ __launch_bounds__(256) void sig_kernel(const float* __restrict__ x,
        const float* __restrict__ cw, const float* __restrict__ cb,
        float* __restrict__ sig /*[256][7380]*/) {
    __shared__ float inc[TT][9];
    __shared__ float S2[2][81];
    const int p = blockIdx.x;
    const int b = p >> 2, oc = p & 3;
    const int tid = threadIdx.x;

    const float w0 = cw[oc * 4 + 0], w1 = cw[oc * 4 + 1];
    const float w2 = cw[oc * 4 + 2], w3 = cw[oc * 4 + 3];
    const float bias = cb[oc];
    const float* xb = x + (long)b * TT * IN_CH;

    // increments (basepoint=True: first increment is y[0] itself)
    for (int it = tid; it < TT * 8; it += 256) {
        const int t = it >> 3, ch = it & 7;
        const float* xp = xb + t * IN_CH + ch * 4;
        float y = xp[0] * w0 + xp[1] * w1 + xp[2] * w2 + xp[3] * w3 + bias;
        float v;
        if (t == 0) {
            v = y;
        } else {
            const float* xq = xp - IN_CH;
            float ym = xq[0] * w0 + xq[1] * w1 + xq[2] * w2 + xq[3] * w3 + bias;
            v = y - ym;
        }
        inc[t][1 + ch] = v;
    }
    for (int t = tid; t < TT; t += 256) inc[t][0] = (t == 0) ? 0.f : (1.f / 127.f);
    if (tid < 81) S2[0][tid] = 0.f;

    float S1r[9];
#pragma unroll
    for (int c = 0; c < 9; c++) S1r[c] = 0.f;
    float S3r[3] = {0.f, 0.f, 0.f};
    float S4r[3][9];
#pragma unroll
    for (int q = 0; q < 3; q++)
#pragma unroll
        for (int i = 0; i < 9; i++) S4r[q][i] = 0.f;

    int i1a[3], i2a[3], i3a[3];
    const bool active = tid < 243;
#pragma unroll
    for (int q = 0; q < 3; q++) {
        int tr = tid + q * 243;
        i3a[q] = tr % 9; i2a[q] = (tr / 9) % 9; i1a[q] = tr / 81;
    }
    __syncthreads();

    int buf = 0;
    for (int t = 0; t < TT; ++t) {
        float dx[9];
#pragma unroll
        for (int c = 0; c < 9; c++) dx[c] = inc[t][c];
        if (active) {
#pragma unroll
            for (int q = 0; q < 3; q++) {
                const int i1 = i1a[q], i2 = i2a[q], i3 = i3a[q];
                const float s2v = S2[buf][i1 * 9 + i2];
                const float t12 = dx[i1] * dx[i2];
                const float s1d2 = S1r[i1] * dx[i2];
                const float K2 = t12 * (1.f / 6.f) + s1d2 * 0.5f + s2v;
                const float K = dx[i3] * (t12 * (1.f / 24.f) + s1d2 * (1.f / 6.f) + s2v * 0.5f) + S3r[q];
#pragma unroll
                for (int i4 = 0; i4 < 9; i4++) S4r[q][i4] += K * dx[i4];
                S3r[q] += K2 * dx[i3];
            }
        }
        if (tid < 81) {
            const int i = tid / 9, j = tid % 9;
            S2[buf ^ 1][tid] = S2[buf][tid] + dx[j] * (dx[i] * 0.5f + S1r[i]);
        }
#pragma unroll
        for (int c = 0; c < 9; c++) S1r[c] += dx[c];
        __syncthreads();
        buf ^= 1;
    }

    float* sp = sig + (long)p * SIGCH;
    if (tid < 9) sp[tid] = S1r[tid];
    if (tid < 81) sp[9 + tid] = S2[buf][tid];
    if (active) {
#pragma unroll
        for (int q = 0; q < 3; q++) {
            const int tr = tid + q * 243;
            sp[90 + tr] = S3r[q];
#pragma unroll
            for (int i4 = 0; i4 < 9; i4++) sp[819 + tr * 9 + i4] = S4r[q][i4];
        }
    }
}

// ---------------- Kernel 2: GEMM1 partials (K-split) ----------------
__global__ __launch_bounds__(256) void gemm1_kernel(const float* __restrict__ zsig,
        const float* __restrict__ w0, float* __restrict__ part /*[41][64][512]*/) {
    __shared__ float zt[64][52];   // stride 52: 2-way max bank aliasing (free)
    __shared__ float wt[BK][16];
    const int nt = blockIdx.x, kc = blockIdx.y;
    const int n0 = nt * 16, k0 = kc * KCH;
    const int tid = threadIdx.x;
    const int col = tid & 15, r4 = (tid >> 4) * 4;
    float acc[4] = {0.f, 0.f, 0.f, 0.f};

    for (int kb = 0; kb < KCH; kb += BK) {
        const int base = k0 + kb;
        for (int i = tid; i < 64 * 12; i += 256) {
            const int row = i / 12, c4 = (i % 12) * 4;
            float4 v = *(const float4*)(zsig + (long)row * K1 + base + c4);
            *(float4*)&zt[row][c4] = v;
        }
        if (tid < BK * 4) {
            const int row = tid >> 2, c4 = (tid & 3) * 4;
            float4 v = *(const float4*)(w0 + (long)(base + row) * N1 + n0 + c4);
            *(float4*)&wt[row][c4] = v;
        }
        __syncthreads();
#pragma unroll 8
        for (int k = 0; k < BK; ++k) {
            const float wv = wt[k][col];
            acc[0] += zt[r4 + 0][k] * wv;
            acc[1] += zt[r4 + 1][k] * wv;
            acc[2] += zt[r4 + 2][k] * wv;
            acc[3] += zt[r4 + 3][k] * wv;
        }
        __syncthreads();
    }
    float* pp = part + ((long)kc * 64 + r4) * N1 + n0 + col;
    pp[0] = acc[0]; pp[N1] = acc[1]; pp[2 * N1] = acc[2]; pp[3 * N1] = acc[3];
}

// ---------------- Kernel 3: reduce K-split partials + bias + sigmoid ----------------
__global__ __launch_bounds__(256) void red1_kernel(const float* __restrict__ part,
        const float* __restrict__ b0v, float* __restrict__ z1) {
    const int idx = blockIdx.x * 256 + threadIdx.x;  // 64*512
    const int n = idx & (N1 - 1);
    float s = b0v[n];
#pragma unroll 8
    for (int kc = 0; kc < KSPLIT; kc++) s += part[kc * 64 * N1 + idx];
    z1[idx] = 1.f / (1.f + expf(-s));
}

// ---------------- Kernel 4: GEMM2 + bias + sigmoid ----------------
__global__ __launch_bounds__(256) void gemm2_kernel(const float* __restrict__ z1,
        const float* __restrict__ w1, const float* __restrict__ b1v,
        float* __restrict__ z2) {
    const int m = blockIdx.x;
    const int n = threadIdx.x;
    float s = b1v[n];
    const float* zr = z1 + m * N1;
#pragma unroll 8
    for (int k = 0; k < N1; k++) s += zr[k] * w1[k * N2 + n];
    z2[m * N2 + n] = 1.f / (1.f + expf(-s));
}

// ---------------- Kernel 5: GEMM3 + log_softmax ----------------
__global__ __launch_bounds__(64) void head_kernel(const float* __restrict__ z2,
        const float* __restrict__ w2, const float* __restrict__ b2v,
        float* __restrict__ out) {
    const int m = blockIdx.x;
    const int tid = threadIdx.x;
    __shared__ float logits[10];
    if (tid < 10) {
        float s = b2v[tid];
        const float* zr = z2 + m * N2;
#pragma unroll 8
        for (int k = 0; k < N2; k++) s += zr[k] * w2[k * 10 + tid];
        logits[tid] = s;
    }
    __syncthreads();
    if (tid == 0) {
        float mx = logits[0];
        for (int j = 1; j < 10; j++) mx = fmaxf(mx, logits[j]);
        float sum = 0.f;
        for (int j = 0; j < 10; j++) sum += expf(logits[j] - mx);
        const float lse = mx + logf(sum);
        for (int j = 0; j < 10; j++) out[m * 10 + j] = logits[j] - lse;
    }
}

extern "C" void kernel_launch(void* const* d_in, const int* in_sizes, int n_in,
                              void* d_out, int out_size, void* d_ws, size_t ws_size,
                              hipStream_t stream) {
    const float* x  = (const float*)d_in[0];
    const float* cw = (const float*)d_in[1];
    const float* cb = (const float*)d_in[2];
    const float* w0 = (const float*)d_in[3];
    const float* b0 = (const float*)d_in[4];
    const float* w1 = (const float*)d_in[5];
    const float* b1 = (const float*)d_in[6];
    const float* w2 = (const float*)d_in[7];
    const float* b2 = (const float*)d_in[8];

    float* ws   = (float*)d_ws;
    float* sig  = ws;                                // 256*7380
    float* part = sig + (long)NPATH * SIGCH;         // 41*64*512
    float* z1   = part + (long)KSPLIT * 64 * N1;     // 64*512
    float* z2   = z1 + 64 * N1;                      // 64*256
    float* out  = (float*)d_out;

    sig_kernel<<<NPATH, 256, 0, stream>>>(x, cw, cb, sig);
    dim3 g2(32, KSPLIT);
    gemm1_kernel<<<g2, 256, 0, stream>>>(sig, w0, part);
    red1_kernel<<<(64 * N1) / 256, 256, 0, stream>>>(part, b0, z1);
    gemm2_kernel<<<64, 256, 0, stream>>>(z1, w1, b1, z2);
    head_kernel<<<64, 64, 0, stream>>>(z2, w2, b2, out);
}

// Round 2
// 155.905 us; speedup vs baseline: 1.3694x; 1.3694x over previous
//
#include <hip/hip_runtime.h>
#include <math.h>

#define TT 128
#define IN_CH 32
#define NPATH 256
#define SIGCH 7380
#define K1 29520
#define N1 512
#define N2 256
#define KSPLIT 30
#define KCH 984
#define BK 24

// ---------------- Kernel 1: conv + time-augment + depth-4 signature ----------------
// One block per path. After staging dx into LDS, each of 243 threads owns 3
// triples (i1,i2,i3..i3+2) sharing (i1,i2) and maintains its OWN running
// S1[i1], S2[i1i2], S3[triple] scalars -> no barriers, no cross-thread deps.
__global__ __launch_bounds__(256, 1) void sig_kernel(const float* __restrict__ x,
        const float* __restrict__ cw, const float* __restrict__ cb,
        float* __restrict__ sig /*[256][7380]*/) {
    __shared__ float inc[TT][12];
    const int p = blockIdx.x;
    const int b = p >> 2, oc = p & 3;
    const int tid = threadIdx.x;

    const float4 wv = *(const float4*)(cw + oc * 4);
    const float bias = cb[oc];
    const float* xb = x + (long)b * TT * IN_CH;

    // dx staging (basepoint=True: first increment is y[0] itself)
    for (int it = tid; it < TT * 8; it += 256) {
        const int t = it >> 3, ch = it & 7;
        const float4 xa = *(const float4*)(xb + t * IN_CH + ch * 4);
        float v = xa.x * wv.x + xa.y * wv.y + xa.z * wv.z + xa.w * wv.w + bias;
        if (t > 0) {
            const float4 xm = *(const float4*)(xb + (t - 1) * IN_CH + ch * 4);
            v -= xm.x * wv.x + xm.y * wv.y + xm.z * wv.z + xm.w * wv.w + bias;
        }
        inc[t][1 + ch] = v;
    }
    for (int t = tid; t < TT; t += 256) inc[t][0] = t ? (1.f / 127.f) : 0.f;
    __syncthreads();

    if (tid >= 243) return;  // no barriers below

    const int base3 = 3 * tid;               // tr = base3 + q, q = 0..2
    const int i1 = base3 / 81;               // shared across q (no carry: (3t)%81<=78)
    const int i2 = (base3 / 9) % 9;          // shared across q
    const int i30 = base3 % 9;               // i3 = i30 + q, stays < 9

    float S4[3][9] = {};
    float s3[3] = {0.f, 0.f, 0.f};
    float s2 = 0.f, s1 = 0.f;

    // software-pipelined: current step's dx in regs, prefetch next
    float4 A0 = *(const float4*)&inc[0][0];
    float4 A1 = *(const float4*)&inc[0][4];
    float A2 = inc[0][8];
    float e1 = inc[0][i1], e2 = inc[0][i2];
    float f0 = inc[0][i30], f1 = inc[0][i30 + 1], f2 = inc[0][i30 + 2];

#pragma unroll 2
    for (int t = 0; t < TT; ++t) {
        const int tn = (t + 1) & (TT - 1);   // last iter prefetch is dummy
        const float4 nA0 = *(const float4*)&inc[tn][0];
        const float4 nA1 = *(const float4*)&inc[tn][4];
        const float nA2 = inc[tn][8];
        const float ne1 = inc[tn][i1], ne2 = inc[tn][i2];
        const float nf0 = inc[tn][i30], nf1 = inc[tn][i30 + 1], nf2 = inc[tn][i30 + 2];

        const float t12 = e1 * e2;
        const float s1d2 = s1 * e2;
        const float Ak = t12 * (1.f / 24.f) + s1d2 * (1.f / 6.f) + s2 * 0.5f;
        const float Bk = t12 * (1.f / 6.f) + s1d2 * 0.5f + s2;

        const float K0 = f0 * Ak + s3[0];
        const float K1v = f1 * Ak + s3[1];
        const float K2v = f2 * Ak + s3[2];

#define UPD(Q, KK) \
        S4[Q][0] += (KK) * A0.x; S4[Q][1] += (KK) * A0.y; \
        S4[Q][2] += (KK) * A0.z; S4[Q][3] += (KK) * A0.w; \
        S4[Q][4] += (KK) * A1.x; S4[Q][5] += (KK) * A1.y; \
        S4[Q][6] += (KK) * A1.z; S4[Q][7] += (KK) * A1.w; \
        S4[Q][8] += (KK) * A2;
        UPD(0, K0) UPD(1, K1v) UPD(2, K2v)
#undef UPD

        s3[0] += Bk * f0; s3[1] += Bk * f1; s3[2] += Bk * f2;
        s2 += e2 * (0.5f * e1 + s1);
        s1 += e1;

        A0 = nA0; A1 = nA1; A2 = nA2;
        e1 = ne1; e2 = ne2; f0 = nf0; f1 = nf1; f2 = nf2;
    }

    float* sp = sig + (long)p * SIGCH;
    if (i2 == 0 && i30 == 0) sp[i1] = s1;
    if (i30 == 0) sp[9 + base3 / 9] = s2;
    sp[90 + base3 + 0] = s3[0];
    sp[90 + base3 + 1] = s3[1];
    sp[90 + base3 + 2] = s3[2];
#pragma unroll
    for (int q = 0; q < 3; q++)
#pragma unroll
        for (int l = 0; l < 9; l++)
            sp[819 + (base3 + q) * 9 + l] = S4[q][l];
}

// ---------------- Kernel 2: GEMM1 partials, 4x4 micro-tile ----------------
__global__ __launch_bounds__(256) void gemm1_kernel(const float* __restrict__ zsig,
        const float* __restrict__ w0, float* __restrict__ part /*[30][64][512]*/) {
    __shared__ float zT[BK][68];   // z transposed: [k][row]
    __shared__ float wt[BK][68];   // [k][col]
    const int nt = blockIdx.x, kc = blockIdx.y;
    const int n0 = nt * 64, k0 = kc * KCH;
    const int tid = threadIdx.x;
    const int c4 = (tid & 15) * 4, r4 = (tid >> 4) * 4;
    float acc[4][4] = {};

    for (int kb = 0; kb < KCH; kb += BK) {
        const int base = k0 + kb;
        __syncthreads();
        for (int i = tid; i < 384; i += 256) {
            const int row = i / 6, cc = (i % 6) * 4;
            float4 v = *(const float4*)(zsig + (long)row * K1 + base + cc);
            zT[cc + 0][row] = v.x; zT[cc + 1][row] = v.y;
            zT[cc + 2][row] = v.z; zT[cc + 3][row] = v.w;
        }
        for (int i = tid; i < 384; i += 256) {
            const int k = i / 16, cc = (i % 16) * 4;
            *(float4*)&wt[k][cc] = *(const float4*)(w0 + (long)(base + k) * N1 + n0 + cc);
        }
        __syncthreads();
#pragma unroll
        for (int k = 0; k < BK; ++k) {
            const float4 zv = *(const float4*)&zT[k][r4];
            const float4 wv = *(const float4*)&wt[k][c4];
            acc[0][0] += zv.x * wv.x; acc[0][1] += zv.x * wv.y; acc[0][2] += zv.x * wv.z; acc[0][3] += zv.x * wv.w;
            acc[1][0] += zv.y * wv.x; acc[1][1] += zv.y * wv.y; acc[1][2] += zv.y * wv.z; acc[1][3] += zv.y * wv.w;
            acc[2][0] += zv.z * wv.x; acc[2][1] += zv.z * wv.y; acc[2][2] += zv.z * wv.z; acc[2][3] += zv.z * wv.w;
            acc[3][0] += zv.w * wv.x; acc[3][1] += zv.w * wv.y; acc[3][2] += zv.w * wv.z; acc[3][3] += zv.w * wv.w;
        }
    }
#pragma unroll
    for (int i = 0; i < 4; i++) {
        float4 o = make_float4(acc[i][0], acc[i][1], acc[i][2], acc[i][3]);
        *(float4*)(part + ((long)kc * 64 + r4 + i) * N1 + n0 + c4) = o;
    }
}

// ---------------- Kernel 3: reduce partials + bias + sigmoid ----------------
__global__ __launch_bounds__(256) void red1_kernel(const float* __restrict__ part,
        const float* __restrict__ b0v, float* __restrict__ z1) {
    const int g = blockIdx.x * 256 + threadIdx.x;   // 8192 float4 groups
    const int n4 = (g & 127) * 4;
    float4 s = *(const float4*)(b0v + n4);
#pragma unroll
    for (int kc = 0; kc < KSPLIT; kc++) {
        float4 pv = *(const float4*)(part + (long)kc * 64 * N1 + g * 4);
        s.x += pv.x; s.y += pv.y; s.z += pv.z; s.w += pv.w;
    }
    float4 o;
    o.x = 1.f / (1.f + expf(-s.x)); o.y = 1.f / (1.f + expf(-s.y));
    o.z = 1.f / (1.f + expf(-s.z)); o.w = 1.f / (1.f + expf(-s.w));
    *(float4*)(z1 + g * 4) = o;
}

// ---------------- Kernel 4: GEMM2 + bias + sigmoid ----------------
__global__ __launch_bounds__(256) void gemm2_kernel(const float* __restrict__ z1,
        const float* __restrict__ w1, const float* __restrict__ b1v,
        float* __restrict__ z2) {
    const int m = blockIdx.x;
    const int n = threadIdx.x;
    float s = b1v[n];
    const float* zr = z1 + m * N1;
#pragma unroll 8
    for (int k = 0; k < N1; k++) s += zr[k] * w1[k * N2 + n];
    z2[m * N2 + n] = 1.f / (1.f + expf(-s));
}

// ---------------- Kernel 5: GEMM3 + log_softmax ----------------
__global__ __launch_bounds__(64) void head_kernel(const float* __restrict__ z2,
        const float* __restrict__ w2, const float* __restrict__ b2v,
        float* __restrict__ out) {
    const int m = blockIdx.x;
    const int tid = threadIdx.x;
    __shared__ float logits[10];
    if (tid < 10) {
        float s = b2v[tid];
        const float* zr = z2 + m * N2;
#pragma unroll 8
        for (int k = 0; k < N2; k++) s += zr[k] * w2[k * 10 + tid];
        logits[tid] = s;
    }
    __syncthreads();
    if (tid == 0) {
        float mx = logits[0];
        for (int j = 1; j < 10; j++) mx = fmaxf(mx, logits[j]);
        float sum = 0.f;
        for (int j = 0; j < 10; j++) sum += expf(logits[j] - mx);
        const float lse = mx + logf(sum);
        for (int j = 0; j < 10; j++) out[m * 10 + j] = logits[j] - lse;
    }
}

extern "C" void kernel_launch(void* const* d_in, const int* in_sizes, int n_in,
                              void* d_out, int out_size, void* d_ws, size_t ws_size,
                              hipStream_t stream) {
    const float* x  = (const float*)d_in[0];
    const float* cw = (const float*)d_in[1];
    const float* cb = (const float*)d_in[2];
    const float* w0 = (const float*)d_in[3];
    const float* b0 = (const float*)d_in[4];
    const float* w1 = (const float*)d_in[5];
    const float* b1 = (const float*)d_in[6];
    const float* w2 = (const float*)d_in[7];
    const float* b2 = (const float*)d_in[8];

    float* ws   = (float*)d_ws;
    float* sig  = ws;                                // 256*7380
    float* part = sig + (long)NPATH * SIGCH;         // 30*64*512
    float* z1   = part + (long)KSPLIT * 64 * N1;     // 64*512
    float* z2   = z1 + 64 * N1;                      // 64*256
    float* out  = (float*)d_out;

    sig_kernel<<<NPATH, 256, 0, stream>>>(x, cw, cb, sig);
    gemm1_kernel<<<dim3(8, KSPLIT), 256, 0, stream>>>(sig, w0, part);
    red1_kernel<<<32, 256, 0, stream>>>(part, b0, z1);
    gemm2_kernel<<<64, 256, 0, stream>>>(z1, w1, b1, z2);
    head_kernel<<<64, 64, 0, stream>>>(z2, w2, b2, out);
}

// Round 3
// 92.272 us; speedup vs baseline: 2.3138x; 1.6896x over previous
//
#include <hip/hip_runtime.h>
#include <math.h>

#define TT 128
#define IN_CH 32
#define NPATH 256
#define SIGCH 7380
#define K1 29520
#define N1 512
#define N2 256
#define BK 24

// ---------------- Kernel 1: conv + time-augment + depth-4 signature ----------------
// One block per path. After staging dx into LDS, each of 243 threads owns 3
// triples (i1,i2,i3..i3+2) sharing (i1,i2) and maintains its OWN running
// S1[i1], S2[i1i2], S3[triple] scalars -> no barriers, no cross-thread deps.
__global__ __launch_bounds__(256, 1) void sig_kernel(const float* __restrict__ x,
        const float* __restrict__ cw, const float* __restrict__ cb,
        float* __restrict__ sig /*[256][7380]*/) {
    __shared__ float inc[TT][12];
    const int p = blockIdx.x;
    const int b = p >> 2, oc = p & 3;
    const int tid = threadIdx.x;

    const float4 wv = *(const float4*)(cw + oc * 4);
    const float bias = cb[oc];
    const float* xb = x + (long)b * TT * IN_CH;

    // dx staging (basepoint=True: first increment is y[0] itself)
    for (int it = tid; it < TT * 8; it += 256) {
        const int t = it >> 3, ch = it & 7;
        const float4 xa = *(const float4*)(xb + t * IN_CH + ch * 4);
        float v = xa.x * wv.x + xa.y * wv.y + xa.z * wv.z + xa.w * wv.w + bias;
        if (t > 0) {
            const float4 xm = *(const float4*)(xb + (t - 1) * IN_CH + ch * 4);
            v -= xm.x * wv.x + xm.y * wv.y + xm.z * wv.z + xm.w * wv.w + bias;
        }
        inc[t][1 + ch] = v;
    }
    for (int t = tid; t < TT; t += 256) inc[t][0] = t ? (1.f / 127.f) : 0.f;
    __syncthreads();

    if (tid >= 243) return;  // no barriers below

    const int base3 = 3 * tid;               // tr = base3 + q, q = 0..2
    const int i1 = base3 / 81;               // shared across q
    const int i2 = (base3 / 9) % 9;          // shared across q
    const int i30 = base3 % 9;               // i3 = i30 + q, stays < 9

    float S4[3][9] = {};
    float s3[3] = {0.f, 0.f, 0.f};
    float s2 = 0.f, s1 = 0.f;

    float4 A0 = *(const float4*)&inc[0][0];
    float4 A1 = *(const float4*)&inc[0][4];
    float A2 = inc[0][8];
    float e1 = inc[0][i1], e2 = inc[0][i2];
    float f0 = inc[0][i30], f1 = inc[0][i30 + 1], f2 = inc[0][i30 + 2];

#pragma unroll 2
    for (int t = 0; t < TT; ++t) {
        const int tn = (t + 1) & (TT - 1);
        const float4 nA0 = *(const float4*)&inc[tn][0];
        const float4 nA1 = *(const float4*)&inc[tn][4];
        const float nA2 = inc[tn][8];
        const float ne1 = inc[tn][i1], ne2 = inc[tn][i2];
        const float nf0 = inc[tn][i30], nf1 = inc[tn][i30 + 1], nf2 = inc[tn][i30 + 2];

        const float t12 = e1 * e2;
        const float s1d2 = s1 * e2;
        const float Ak = t12 * (1.f / 24.f) + s1d2 * (1.f / 6.f) + s2 * 0.5f;
        const float Bk = t12 * (1.f / 6.f) + s1d2 * 0.5f + s2;

        const float K0 = f0 * Ak + s3[0];
        const float K1v = f1 * Ak + s3[1];
        const float K2v = f2 * Ak + s3[2];

#define UPD(Q, KK) \
        S4[Q][0] += (KK) * A0.x; S4[Q][1] += (KK) * A0.y; \
        S4[Q][2] += (KK) * A0.z; S4[Q][3] += (KK) * A0.w; \
        S4[Q][4] += (KK) * A1.x; S4[Q][5] += (KK) * A1.y; \
        S4[Q][6] += (KK) * A1.z; S4[Q][7] += (KK) * A1.w; \
        S4[Q][8] += (KK) * A2;
        UPD(0, K0) UPD(1, K1v) UPD(2, K2v)
#undef UPD

        s3[0] += Bk * f0; s3[1] += Bk * f1; s3[2] += Bk * f2;
        s2 += e2 * (0.5f * e1 + s1);
        s1 += e1;

        A0 = nA0; A1 = nA1; A2 = nA2;
        e1 = ne1; e2 = ne2; f0 = nf0; f1 = nf1; f2 = nf2;
    }

    float* sp = sig + (long)p * SIGCH;
    if (i2 == 0 && i30 == 0) sp[i1] = s1;
    if (i30 == 0) sp[9 + base3 / 9] = s2;
    sp[90 + base3 + 0] = s3[0];
    sp[90 + base3 + 1] = s3[1];
    sp[90 + base3 + 2] = s3[2];
#pragma unroll
    for (int q = 0; q < 3; q++)
#pragma unroll
        for (int l = 0; l < 9; l++)
            sp[819 + (base3 + q) * 9 + l] = S4[q][l];
}

// ---------------- Kernel 2: GEMM1 partials, 4x4 micro-tile, big K-split ----------------
__global__ __launch_bounds__(256) void gemm1_kernel(const float* __restrict__ zsig,
        const float* __restrict__ w0, float* __restrict__ part, int KCH) {
    __shared__ float zT[BK][68];   // z transposed: [k][row]
    __shared__ float wt[BK][68];   // [k][col]
    const int nt = blockIdx.x, kc = blockIdx.y;
    const int n0 = nt * 64, k0 = kc * KCH;
    const int tid = threadIdx.x;
    const int c4 = (tid & 15) * 4, r4 = (tid >> 4) * 4;
    float acc[4][4] = {};

    for (int kb = 0; kb < KCH; kb += BK) {
        const int base = k0 + kb;
        __syncthreads();
        for (int i = tid; i < 384; i += 256) {
            const int row = i / 6, cc = (i % 6) * 4;
            float4 v = *(const float4*)(zsig + (long)row * K1 + base + cc);
            zT[cc + 0][row] = v.x; zT[cc + 1][row] = v.y;
            zT[cc + 2][row] = v.z; zT[cc + 3][row] = v.w;
        }
        for (int i = tid; i < 384; i += 256) {
            const int k = i / 16, cc = (i % 16) * 4;
            *(float4*)&wt[k][cc] = *(const float4*)(w0 + (long)(base + k) * N1 + n0 + cc);
        }
        __syncthreads();
#pragma unroll
        for (int k = 0; k < BK; ++k) {
            const float4 zv = *(const float4*)&zT[k][r4];
            const float4 wvv = *(const float4*)&wt[k][c4];
            acc[0][0] += zv.x * wvv.x; acc[0][1] += zv.x * wvv.y; acc[0][2] += zv.x * wvv.z; acc[0][3] += zv.x * wvv.w;
            acc[1][0] += zv.y * wvv.x; acc[1][1] += zv.y * wvv.y; acc[1][2] += zv.y * wvv.z; acc[1][3] += zv.y * wvv.w;
            acc[2][0] += zv.z * wvv.x; acc[2][1] += zv.z * wvv.y; acc[2][2] += zv.z * wvv.z; acc[2][3] += zv.z * wvv.w;
            acc[3][0] += zv.w * wvv.x; acc[3][1] += zv.w * wvv.y; acc[3][2] += zv.w * wvv.z; acc[3][3] += zv.w * wvv.w;
        }
    }
#pragma unroll
    for (int i = 0; i < 4; i++) {
        float4 o = make_float4(acc[i][0], acc[i][1], acc[i][2], acc[i][3]);
        *(float4*)(part + ((long)kc * 64 + r4 + i) * N1 + n0 + c4) = o;
    }
}

// ---------------- Kernel 3: reduce partials + bias + sigmoid ----------------
// 256 blocks x 256 threads; block owns 32 float4 outputs, 8-way k-slice tree.
__global__ __launch_bounds__(256) void red1_kernel(const float* __restrict__ part,
        const float* __restrict__ b0v, float* __restrict__ z1, int ksplit) {
    __shared__ float4 red[256];
    const int tid = threadIdx.x;
    const int g = tid & 31, s = tid >> 5;
    const int gg = blockIdx.x * 32 + g;           // float4 index in [0, 8192)
    const int per = (ksplit + 7) >> 3;
    const int ks = s * per, ke = min(ksplit, ks + per);
    float4 a = make_float4(0.f, 0.f, 0.f, 0.f);
    for (int kc = ks; kc < ke; kc++) {
        float4 pv = *(const float4*)(part + ((long)kc * 8192 + gg) * 4);
        a.x += pv.x; a.y += pv.y; a.z += pv.z; a.w += pv.w;
    }
    red[tid] = a;
    __syncthreads();
    if (tid < 128) { float4 o = red[tid + 128]; red[tid].x += o.x; red[tid].y += o.y; red[tid].z += o.z; red[tid].w += o.w; }
    __syncthreads();
    if (tid < 64) { float4 o = red[tid + 64]; red[tid].x += o.x; red[tid].y += o.y; red[tid].z += o.z; red[tid].w += o.w; }
    __syncthreads();
    if (tid < 32) {
        float4 sum = red[tid];
        float4 o = red[tid + 32];
        sum.x += o.x; sum.y += o.y; sum.z += o.z; sum.w += o.w;
        const float4 bv = *(const float4*)(b0v + (gg & 127) * 4);
        float4 r;
        r.x = 1.f / (1.f + expf(-(sum.x + bv.x)));
        r.y = 1.f / (1.f + expf(-(sum.y + bv.y)));
        r.z = 1.f / (1.f + expf(-(sum.z + bv.z)));
        r.w = 1.f / (1.f + expf(-(sum.w + bv.w)));
        *(float4*)(z1 + gg * 4) = r;
    }
}

// ---------------- Kernel 4: GEMM2 + bias + sigmoid (in-block K-split) ----------------
__global__ __launch_bounds__(256) void gemm2_kernel(const float* __restrict__ z1,
        const float* __restrict__ w1, const float* __restrict__ b1v,
        float* __restrict__ z2) {
    __shared__ float red[256];
    const int m = blockIdx.x >> 2, nq = blockIdx.x & 3;
    const int tid = threadIdx.x;
    const int c = tid & 63, s = tid >> 6;
    const int n = nq * 64 + c;
    const float* zr = z1 + m * N1 + s * 128;
    const float* wr = w1 + (long)(s * 128) * N2 + n;
    float acc = 0.f;
#pragma unroll 16
    for (int k = 0; k < 128; k++) acc += zr[k] * wr[(long)k * N2];
    red[tid] = acc;
    __syncthreads();
    if (tid < 128) red[tid] += red[tid + 128];
    __syncthreads();
    if (tid < 64) {
        float sum = red[tid] + red[tid + 64] + b1v[n];
        z2[m * N2 + n] = 1.f / (1.f + expf(-sum));
    }
}

// ---------------- Kernel 5: GEMM3 + log_softmax ----------------
__global__ __launch_bounds__(64) void head_kernel(const float* __restrict__ z2,
        const float* __restrict__ w2, const float* __restrict__ b2v,
        float* __restrict__ out) {
    const int m = blockIdx.x;
    const int tid = threadIdx.x;
    __shared__ float logits[10];
    if (tid < 10) {
        float s = b2v[tid];
        const float* zr = z2 + m * N2;
#pragma unroll 8
        for (int k = 0; k < N2; k++) s += zr[k] * w2[k * 10 + tid];
        logits[tid] = s;
    }
    __syncthreads();
    if (tid == 0) {
        float mx = logits[0];
        for (int j = 1; j < 10; j++) mx = fmaxf(mx, logits[j]);
        float sum = 0.f;
        for (int j = 0; j < 10; j++) sum += expf(logits[j] - mx);
        const float lse = mx + logf(sum);
        for (int j = 0; j < 10; j++) out[m * 10 + j] = logits[j] - lse;
    }
}

extern "C" void kernel_launch(void* const* d_in, const int* in_sizes, int n_in,
                              void* d_out, int out_size, void* d_ws, size_t ws_size,
                              hipStream_t stream) {
    const float* x  = (const float*)d_in[0];
    const float* cw = (const float*)d_in[1];
    const float* cb = (const float*)d_in[2];
    const float* w0 = (const float*)d_in[3];
    const float* b0 = (const float*)d_in[4];
    const float* w1 = (const float*)d_in[5];
    const float* b1 = (const float*)d_in[6];
    const float* w2 = (const float*)d_in[7];
    const float* b2 = (const float*)d_in[8];

    // tiered K-split by available workspace (29520 = KSPLIT * KCH, KCH % 24 == 0)
    const size_t fixed = (size_t)NPATH * SIGCH + 64 * N1 + 64 * N2;  // sig + z1 + z2 (floats)
    int ksplit = 41, kch = 720;
    if (ws_size >= (fixed + (size_t)123 * 64 * N1) * 4) { ksplit = 123; kch = 240; }
    else if (ws_size >= (fixed + (size_t)82 * 64 * N1) * 4) { ksplit = 82; kch = 360; }

    float* ws   = (float*)d_ws;
    float* sig  = ws;                                // 256*7380
    float* part = sig + (long)NPATH * SIGCH;         // ksplit*64*512
    float* z1   = part + (long)ksplit * 64 * N1;     // 64*512
    float* z2   = z1 + 64 * N1;                      // 64*256
    float* out  = (float*)d_out;

    sig_kernel<<<NPATH, 256, 0, stream>>>(x, cw, cb, sig);
    gemm1_kernel<<<dim3(8, ksplit), 256, 0, stream>>>(sig, w0, part, kch);
    red1_kernel<<<256, 256, 0, stream>>>(part, b0, z1, ksplit);
    gemm2_kernel<<<256, 256, 0, stream>>>(z1, w1, b1, z2);
    head_kernel<<<64, 64, 0, stream>>>(z2, w2, b2, out);
}